// Round 9
// baseline (53.242 us; speedup 1.0000x reference)
//
#include <hip/hip_runtime.h>

// TreeLoss: 2-level hierarchical softmax loss.
// z(b)    = 1 + sum_p e^{x_p} * (1 + sum_{c in p} e^{x_c})   (parents p=56..63)
// loss(b) = log(z / (e^{x_g} * e^{x_parent(g)})),  parent(g) = 56 + g/7.
//
// R9 = R8's stage/compute body, single-kernel. Grid-stride (1024 blocks x
// 4 waves, 2 tiles of 32 rows per wave); last-arriving block does the final
// 1024-partial reduction in fixed order (deterministic). Unlike R4's fused
// attempt (48us): only thread 0 waits on the returning fetch_add; waves 1-3
// retire right after the wsum barrier, wave 0 learns the flag via intra-wave
// __shfl -- no block-wide wait holding LDS through the atomic round-trip,
// and the 1024 RMWs arrive spread over the kernel, not as a convoy.

#define THREADS 256               // 4 waves
#define WROWS   32                // rows per wave-tile
#define STRIDE  68                // floats; 272B rows, 16B-aligned
#define BLOCKS  1024

__device__ __forceinline__ float elem(const float4& v, int j) {
    return j == 0 ? v.x : j == 1 ? v.y : j == 2 ? v.z : v.w;
}

__global__ void __launch_bounds__(THREADS) tree_loss(
    const float* __restrict__ pred,    // [rows, 64]
    const int*   __restrict__ gt,      // [rows] 0..55
    float*       __restrict__ partial, // [gridDim.x]
    int*         __restrict__ counter, // zeroed via async memset each call
    float*       __restrict__ out,
    int rows, float inv)
{
    __shared__ float lds[4 * WROWS * STRIDE];   // 34816 B -> 4 blocks/CU
    __shared__ float wsum[4];

    const int t = threadIdx.x;
    const int w = t >> 6;
    const int l = t & 63;
    float* e_base = &lds[w * WROWS * STRIDE];

    const int nwaves = (int)gridDim.x * 4;
    const int ntiles = (rows + WROWS - 1) / WROWS;   // 8192

    float acc = 0.f;
    for (int tile = (int)blockIdx.x * 4 + w; tile < ntiles; tile += nwaves) {
        const int waveRowBase = tile * WROWS;
        const bool full = (waveRowBase + WROWS <= rows);

        // ---- Stage (wave-private): 32 rows = 512 float4 / 64 lanes = 8 each.
        const float4* p4 = (const float4*)pred + (size_t)waveRowBase * 16;
        float4 v[8];
        #pragma unroll
        for (int i = 0; i < 8; ++i) {
            const int f = i * 64 + l;
            v[i] = (full || waveRowBase + (f >> 4) < rows)
                     ? p4[f] : make_float4(0.f, 0.f, 0.f, 0.f);
        }
        #pragma unroll
        for (int i = 0; i < 8; ++i) {
            const int f   = i * 64 + l;
            const int row = f >> 4;
            const int c4  = (f & 15) << 2;
            float4 ef;
            ef.x = __expf(v[i].x); ef.y = __expf(v[i].y);
            ef.z = __expf(v[i].z); ef.w = __expf(v[i].w);
            *(float4*)(e_base + row * STRIDE + c4) = ef;   // ds_write_b128
        }
        // No barrier: same wave wrote, same wave reads (compiler lgkmcnt).

        // ---- Compute: 2 lanes per row; hi=0 -> parents 0-3, hi=1 -> 4-7.
        const int r  = l & 31;
        const int hi = l >> 5;
        const float* e = e_base + r * STRIDE;

        float4 ch[7];
        #pragma unroll
        for (int k = 0; k < 7; ++k)
            ch[k] = *(const float4*)(e + hi * 28 + 4 * k);  // ds_read_b128
        const float4 pv = *(const float4*)(e + 56 + 4 * hi);

        float zh = 0.f;
        #pragma unroll
        for (int p = 0; p < 4; ++p) {
            float s = 1.f;
            #pragma unroll
            for (int c = 0; c < 7; ++c) {
                const int idx = p * 7 + c;
                s += elem(ch[idx >> 2], idx & 3);
            }
            zh += elem(pv, p) * s;
        }
        const float zo = __shfl_xor(zh, 32);

        const int  rowg  = waveRowBase + r;
        const bool valid = (rowg < rows);
        if (hi == 0 && valid) {
            const int g = gt[rowg];                 // lanes 0..31, coalesced
            const float z = 1.f + zh + zo;
            const float m = e[g] * e[56 + g / 7];
            acc += __logf(z / m);
        }
    }

    // ---- Wave + block reduction.
    #pragma unroll
    for (int off = 32; off; off >>= 1) acc += __shfl_xor(acc, off);
    if (l == 0) wsum[w] = acc;
    __syncthreads();
    // Waves 1-3 are done and retire here, releasing SIMD slots.

    if (w == 0) {
        int old = 0;
        if (t == 0) {
            const float b = wsum[0] + wsum[1] + wsum[2] + wsum[3];
            __hip_atomic_store(&partial[blockIdx.x], b,
                               __ATOMIC_RELEASE, __HIP_MEMORY_SCOPE_AGENT);
            old = __hip_atomic_fetch_add(counter, 1,
                                         __ATOMIC_ACQ_REL, __HIP_MEMORY_SCOPE_AGENT);
        }
        old = __shfl(old, 0);                       // intra-wave, no barrier
        if (old == (int)gridDim.x - 1) {
            // Last block: deterministic fixed-order sum of all partials.
            float s = 0.f;
            for (int i = l; i < (int)gridDim.x; i += 64)
                s += __hip_atomic_load(&partial[i],
                                       __ATOMIC_ACQUIRE, __HIP_MEMORY_SCOPE_AGENT);
            #pragma unroll
            for (int off = 32; off; off >>= 1) s += __shfl_xor(s, off);
            if (l == 0) out[0] = s * inv;
        }
    }
}

extern "C" void kernel_launch(void* const* d_in, const int* in_sizes, int n_in,
                              void* d_out, int out_size, void* d_ws, size_t ws_size,
                              hipStream_t stream) {
    const float* pred = (const float*)d_in[0];   // [B,64] fp32
    const int*   gt   = (const int*)d_in[1];     // [B] int32
    float* out = (float*)d_out;
    const int rows = in_sizes[1];                // BATCH = 262144

    float* partial = (float*)d_ws;
    int*   counter = (int*)((char*)d_ws + 4096); // past partial[1024]

    hipMemsetAsync(counter, 0, sizeof(int), stream);  // graph-capturable
    tree_loss<<<BLOCKS, THREADS, 0, stream>>>(
        pred, gt, partial, counter, out, rows, 1.0f / (float)rows);
}

// Round 10
// 20.427 us; speedup vs baseline: 2.6065x; 2.6065x over previous
//
#include <hip/hip_runtime.h>

// TreeLoss: 2-level hierarchical softmax loss.
// z(b)    = 1 + sum_p e^{x_p} * (1 + sum_{c in p} e^{x_c})   (parents p=56..63)
// loss(b) = log(z / (e^{x_g} * e^{x_parent(g)})),  parent(g) = 56 + g/7.
//
// R10 = R8 body + per-wave software pipelining, two kernels (R4/R9 proved
// agent-scope atomic handshakes serialize block retirement: 66us with zero
// HBM fetch). Each wave processes TWO 32-row tiles: tile1's 8 global loads
// are issued BEFORE tile0's compute phase, so HBM latency hides under the
// ~600cyc exp/ds_read/VALU of tile0. Per-wave DS ordering makes the
// write(tile1)-after-read(tile0) LDS reuse hazard-free. Stride 68 floats:
// 16B-aligned rows -> b128 LDS ops, uniform 8-access/bank (R9 counters:
// 39K conflicts = clean). Blocks own 256 contiguous rows.

#define THREADS 256               // 4 waves
#define WROWS   32                // rows per tile
#define STRIDE  68                // floats; 272B rows, 16B-aligned

__device__ __forceinline__ float elem(const float4& v, int j) {
    return j == 0 ? v.x : j == 1 ? v.y : j == 2 ? v.z : v.w;
}

__device__ __forceinline__ void load_tile(float4 (&v)[8], const float* __restrict__ pred,
                                          int rowBase, int rows, int l) {
    const float4* p4 = (const float4*)pred + (size_t)rowBase * 16;
    const bool full = (rowBase + WROWS <= rows);
    #pragma unroll
    for (int i = 0; i < 8; ++i) {
        const int f = i * 64 + l;
        v[i] = (full || rowBase + (f >> 4) < rows)
                 ? p4[f] : make_float4(0.f, 0.f, 0.f, 0.f);
    }
}

__device__ __forceinline__ void exp_write(const float4 (&v)[8], float* e_base, int l) {
    #pragma unroll
    for (int i = 0; i < 8; ++i) {
        const int f   = i * 64 + l;
        const int row = f >> 4;
        const int c4  = (f & 15) << 2;
        float4 ef;
        ef.x = __expf(v[i].x); ef.y = __expf(v[i].y);
        ef.z = __expf(v[i].z); ef.w = __expf(v[i].w);
        *(float4*)(e_base + row * STRIDE + c4) = ef;   // ds_write_b128
    }
}

__device__ __forceinline__ float compute_tile(const float* e_base,
                                              const int* __restrict__ gt,
                                              int rowBase, int rows, int l) {
    const int r  = l & 31;
    const int hi = l >> 5;
    const float* e = e_base + r * STRIDE;

    float4 ch[7];
    #pragma unroll
    for (int k = 0; k < 7; ++k)
        ch[k] = *(const float4*)(e + hi * 28 + 4 * k);  // ds_read_b128
    const float4 pv = *(const float4*)(e + 56 + 4 * hi);

    float zh = 0.f;
    #pragma unroll
    for (int p = 0; p < 4; ++p) {
        float s = 1.f;
        #pragma unroll
        for (int c = 0; c < 7; ++c) {
            const int idx = p * 7 + c;                  // compile-time
            s += elem(ch[idx >> 2], idx & 3);
        }
        zh += elem(pv, p) * s;
    }
    const float zo = __shfl_xor(zh, 32);

    float loss = 0.f;
    const int rowg = rowBase + r;
    if (hi == 0 && rowg < rows) {
        const int g = gt[rowg];                         // lanes 0..31, coalesced
        loss = __logf((1.f + zh + zo) / (e[g] * e[56 + g / 7]));
    }
    return loss;
}

__global__ void __launch_bounds__(THREADS) tree_loss_partial(
    const float* __restrict__ pred,   // [rows, 64]
    const int*   __restrict__ gt,     // [rows] 0..55
    float*       __restrict__ partial,// [gridDim.x]
    int rows)
{
    __shared__ float lds[4 * WROWS * STRIDE];   // 34816 B -> 4 blocks/CU
    __shared__ float wsum[4];

    const int t = threadIdx.x;
    const int w = t >> 6;
    const int l = t & 63;
    float* e_base = &lds[w * WROWS * STRIDE];

    const int ntiles = (rows + WROWS - 1) / WROWS;
    const int tile0  = (int)blockIdx.x * 8 + w;        // block owns tiles 8b..8b+7
    const int tile1  = tile0 + 4;
    const bool has0  = tile0 < ntiles;
    const bool has1  = tile1 < ntiles;
    const int rb0 = tile0 * WROWS, rb1 = tile1 * WROWS;

    float acc = 0.f;
    float4 vA[8], vB[8];

    if (has0) load_tile(vA, pred, rb0, rows, l);
    if (has0) exp_write(vA, e_base, l);
    if (has1) load_tile(vB, pred, rb1, rows, l);   // prefetch: overlaps compute0
    if (has0) acc += compute_tile(e_base, gt, rb0, rows, l);
    if (has1) {
        exp_write(vB, e_base, l);                  // in-order DS: safe reuse
        acc += compute_tile(e_base, gt, rb1, rows, l);
    }

    // ---- Wave + block reduction.
    #pragma unroll
    for (int off = 32; off; off >>= 1) acc += __shfl_xor(acc, off);
    if (l == 0) wsum[w] = acc;
    __syncthreads();
    if (t == 0) partial[blockIdx.x] = wsum[0] + wsum[1] + wsum[2] + wsum[3];
}

__global__ void __launch_bounds__(256) tree_loss_final(
    const float* __restrict__ partial, int n,
    float* __restrict__ out, float inv)
{
    float s = 0.0f;
    for (int i = threadIdx.x; i < n; i += 256) s += partial[i];
    #pragma unroll
    for (int off = 32; off; off >>= 1) s += __shfl_xor(s, off);
    __shared__ float w[4];
    const int lane = threadIdx.x & 63;
    const int wv   = threadIdx.x >> 6;
    if (lane == 0) w[wv] = s;
    __syncthreads();
    if (threadIdx.x == 0) out[0] = (w[0] + w[1] + w[2] + w[3]) * inv;
}

extern "C" void kernel_launch(void* const* d_in, const int* in_sizes, int n_in,
                              void* d_out, int out_size, void* d_ws, size_t ws_size,
                              hipStream_t stream) {
    const float* pred = (const float*)d_in[0];   // [B,64] fp32
    const int*   gt   = (const int*)d_in[1];     // [B] int32
    float* out     = (float*)d_out;
    float* partial = (float*)d_ws;
    const int rows = in_sizes[1];                // BATCH = 262144

    const int ntiles = (rows + WROWS - 1) / WROWS;
    const int blocks = (ntiles + 7) / 8;         // 1024
    tree_loss_partial<<<blocks, THREADS, 0, stream>>>(pred, gt, partial, rows);
    tree_loss_final<<<1, 256, 0, stream>>>(partial, blocks, out, 1.0f / (float)rows);
}

// Round 11
// 20.084 us; speedup vs baseline: 2.6510x; 1.0171x over previous
//
#include <hip/hip_runtime.h>

// TreeLoss: 2-level hierarchical softmax loss.
// z(b)    = 1 + sum_p e^{x_p} * (1 + sum_{c in p} e^{x_c})   (parents p=56..63)
// loss(b) = log z - (x_g + x_parent(g)),  parent(g) = 56 + g/7; out = mean.
//
// R11: global_load_lds direct HBM->LDS staging (no VGPR round trip, no
// exp-on-staging-path). Raw x staged; exp moved to compute; marginal is
// log z - x_g - x_p (plain x reads). DMA dest must be linear, so bank
// conflicts are fixed by XOR-swizzling the GLOBAL SOURCE chunk index
// (sc = chunk ^ (row&7), line-local => coalescing intact) and applying the
// same involution on LDS reads (rule: both-sides-or-neither).
// Per wave: 2 LDS regions; all 16 DMAs issued up-front; counted waits
// (vmcnt(8) -> compute A -> vmcnt(0) -> compute B) hide tile-B latency
// under compute-A. No __syncthreads at all; per-wave partials.

#define THREADS 256               // 4 waves
#define WROWS   32                // rows per tile
#define RPB     256               // rows per block (4 waves x 2 tiles x 32)

__device__ __forceinline__ float elem(const float4& v, int j) {
    return j == 0 ? v.x : j == 1 ? v.y : j == 2 ? v.z : v.w;
}

__device__ __forceinline__ void stage_tile(const float* __restrict__ pred,
                                           int rowBase, float* ldsReg,
                                           int l, int rows) {
    #pragma unroll
    for (int i = 0; i < 8; ++i) {
        const int f   = i * 64 + l;          // LDS chunk slot 0..511
        const int rr  = f >> 4;              // tile row 0..31
        const int sc  = (f & 15) ^ (rr & 7); // pre-swizzled source chunk
        const int row = rowBase + rr;
        if (row < rows) {
            const float* src = pred + (size_t)row * 64 + sc * 4;
            __builtin_amdgcn_global_load_lds(
                (const __attribute__((address_space(1))) float*)src,
                (__attribute__((address_space(3))) float*)(ldsReg + i * 256),
                16, 0, 0);                   // lane l lands at +l*16B = slot f
        }
    }
}

// One row is handled by 2 lanes (r = l&31 selects row, hi = l>>5 selects
// parents 0-3 / 4-7). Returns loss (meaningful in hi==0 lanes).
__device__ __forceinline__ float compute_half(const float* ldsReg, int g,
                                              int r, int hi) {
    const int x7 = r & 7;
    const float* rowp = ldsReg + r * 64;

    float4 ch[7];
    #pragma unroll
    for (int k = 0; k < 7; ++k) {
        const int c = (7 * hi + k) ^ x7;               // swizzled read
        ch[k] = *(const float4*)(rowp + c * 4);        // ds_read_b128
    }
    const int cp4 = (14 + hi) ^ x7;
    const float4 pv = *(const float4*)(rowp + cp4 * 4);

    float zh = 0.f;
    #pragma unroll
    for (int p = 0; p < 4; ++p) {
        float s = 1.f;
        #pragma unroll
        for (int c = 0; c < 7; ++c) {
            const int idx = p * 7 + c;                 // compile-time
            s += __expf(elem(ch[idx >> 2], idx & 3));
        }
        zh += __expf(elem(pv, p)) * s;
    }
    const float zo = __shfl_xor(zh, 32);               // other parent-half

    // Marginal: raw x gathers (swizzled scalar reads).
    const int cg = (g >> 2) ^ x7;
    const float xg = rowp[cg * 4 + (g & 3)];
    const int wp = 56 + g / 7;
    const int cpg = (wp >> 2) ^ x7;
    const float xp = rowp[cpg * 4 + (wp & 3)];

    return __logf(1.f + zh + zo) - xg - xp;
}

__global__ void __launch_bounds__(THREADS) tree_loss_partial(
    const float* __restrict__ pred,   // [rows, 64]
    const int*   __restrict__ gt,     // [rows] 0..55
    float*       __restrict__ partial,// [gridDim.x * 4]
    int rows)
{
    __shared__ float lds[4 * 2 * WROWS * 64];   // 65536 B -> 2 blocks/CU

    const int t  = threadIdx.x;
    const int w  = t >> 6;
    const int l  = t & 63;
    const int r  = l & 31;
    const int hi = l >> 5;

    float* regA = &lds[(w * 2 + 0) * WROWS * 64];
    float* regB = &lds[(w * 2 + 1) * WROWS * 64];

    const int rbA = (int)blockIdx.x * RPB + w * 64;  // wave rows: A, then B
    const int rbB = rbA + WROWS;
    const int rowA = rbA + r, rowB = rbB + r;

    // gt loads FIRST (oldest vmem -> covered by the vmcnt(8) below).
    const int gA = gt[min(rowA, rows - 1)];
    const int gB = gt[min(rowB, rows - 1)];

    // Issue all 16 DMAs back-to-back: 16KB/wave in flight.
    stage_tile(pred, rbA, regA, l, rows);
    stage_tile(pred, rbB, regB, l, rows);

    asm volatile("s_waitcnt vmcnt(8)" ::: "memory");   // gt + tile A done
    const float lossA = compute_half(regA, gA, r, hi);

    asm volatile("s_waitcnt vmcnt(0)" ::: "memory");   // tile B done
    const float lossB = compute_half(regB, gB, r, hi);

    float acc = 0.f;
    if (hi == 0 && rowA < rows) acc += lossA;
    if (hi == 0 && rowB < rows) acc += lossB;

    #pragma unroll
    for (int off = 32; off; off >>= 1) acc += __shfl_xor(acc, off);
    if (l == 0) partial[(size_t)blockIdx.x * 4 + w] = acc;  // per-wave, no barrier
}

__global__ void __launch_bounds__(1024) tree_loss_final(
    const float* __restrict__ partial, int n,
    float* __restrict__ out, float inv)
{
    float s = 0.0f;
    for (int i = threadIdx.x; i < n; i += 1024) s += partial[i];
    #pragma unroll
    for (int off = 32; off; off >>= 1) s += __shfl_xor(s, off);
    __shared__ float w[16];
    const int lane = threadIdx.x & 63;
    const int wv   = threadIdx.x >> 6;
    if (lane == 0) w[wv] = s;
    __syncthreads();
    if (threadIdx.x == 0) {
        float b = 0.f;
        #pragma unroll
        for (int k = 0; k < 16; ++k) b += w[k];
        out[0] = b * inv;
    }
}

extern "C" void kernel_launch(void* const* d_in, const int* in_sizes, int n_in,
                              void* d_out, int out_size, void* d_ws, size_t ws_size,
                              hipStream_t stream) {
    const float* pred = (const float*)d_in[0];   // [B,64] fp32
    const int*   gt   = (const int*)d_in[1];     // [B] int32
    float* out     = (float*)d_out;
    float* partial = (float*)d_ws;
    const int rows = in_sizes[1];                // BATCH = 262144

    const int blocks = (rows + RPB - 1) / RPB;   // 1024
    tree_loss_partial<<<blocks, THREADS, 0, stream>>>(pred, gt, partial, rows);
    tree_loss_final<<<1, 1024, 0, stream>>>(partial, blocks * 4, out,
                                            1.0f / (float)rows);
}